// Round 6
// baseline (210.117 us; speedup 1.0000x reference)
//
#include <hip/hip_runtime.h>

// VQSpeaker: obs[32,2048,128] -> 3-layer MLP -> x[65536,64] -> VQ argmin over
// codebook[2048,64] -> (msg = codebook[idx], idx, cmt_loss).
//
// Round 14: VQ codebook reads go through LDS (T3 minimal 2-phase pipeline).
//   R13 counters: loop still ~55% stalled on per-wave L2 load->use chains;
//   all 4 waves were loading the IDENTICAL codebook stream privately.
//   Now: phase = 2 tiles (4 KB), double-buffered in LDS; each wave issues one
//   1 KB global_load_lds for the NEXT phase, computes the current phase from
//   LDS (ds_read_b128 -> MFMA), then one __syncthreads() per phase (its
//   implicit vmcnt/lgkmcnt drain is the pipeline sync). 4x fewer codebook
//   load instructions; in-loop latency is LDS not L2.
//   e2s LDS staging dropped (back to R12 global e2 reads) -> LDS 38.2 KB,
//   still 4 blocks/CU at launch_bounds(256,4).
//   fp16 single-product screen, candidates, rescore, loss, MLP: R13-verbatim.
//
// d_out layout (float32): msg[4194304] | idx[65536] (as float) | loss[1]
// d_ws: e2[2048] | cbh fp16 256KB | w1h/w1l 16KB ea | w2h/w2l/w3h/w3l 8KB ea

#define NPTS    65536
#define IN_DIM  128
#define HID     64
#define OUT_DIM 64
#define CB_N    2048
#define MSG_ELEMS (NPTS * OUT_DIM)
#define LOSS_SCALE (1.0f / 4194304.0f)
#define MARG 0.5f          // R3-proven screening margin
#define CAND_CAP 512

typedef __attribute__((ext_vector_type(8))) short short8;
typedef _Float16 half8 __attribute__((ext_vector_type(8)));
typedef __attribute__((ext_vector_type(4))) float f32x4;
typedef unsigned int u32;

// async global->LDS, 16B per lane: LDS dest = wave-uniform base + lane*16
__device__ __forceinline__ void gld16(void* lds_base, const void* gsrc) {
    __builtin_amdgcn_global_load_lds(
        (const __attribute__((address_space(1))) u32*)gsrc,
        (__attribute__((address_space(3))) u32*)lds_base, 16, 0, 0);
}

__device__ __forceinline__ unsigned short f2bf(float f) {
    unsigned u = __float_as_uint(f);
    u += 0x7FFF + ((u >> 16) & 1);          // RN-even to bf16
    return (unsigned short)(u >> 16);
}
__device__ __forceinline__ float bf2f(unsigned short h) {
    return __uint_as_float((unsigned)h << 16);
}

// ---- merged prep: blocks 0-15 prep_cb, 16-23 prep_w, 24-31 e2 (+loss=0) ----
__global__ __launch_bounds__(256) void prep_all(
    const float* __restrict__ cb,
    const float* __restrict__ W1, const float* __restrict__ W2,
    const float* __restrict__ W3,
    float* __restrict__ e2,
    _Float16* __restrict__ cbh,
    _Float16* __restrict__ w1h, _Float16* __restrict__ w1l,
    _Float16* __restrict__ w2h, _Float16* __restrict__ w2l,
    _Float16* __restrict__ w3h, _Float16* __restrict__ w3l,
    float* __restrict__ loss)
{
    const int b = blockIdx.x, tid = threadIdx.x;
    if (b < 16) {
        // ---- prep_cb: codebook -> MFMA B-frag order, fp16 hi only ----
        const int id = b * 256 + tid;               // 0..4095: (code n, half h)
        const int n = id >> 1, h = id & 1;
        const int t = n >> 4, l15 = n & 15;
        const float* src = cb + (long)n * OUT_DIM + h * 32;
        #pragma unroll
        for (int quad = 0; quad < 4; ++quad) {
            half8 hi;
            #pragma unroll
            for (int j = 0; j < 8; ++j)
                hi[j] = (_Float16)src[quad * 8 + j];
            const long dst = ((long)(t * 2 + h) * 64 + quad * 16 + l15) * 8;
            *(half8*)(cbh + dst) = hi;
        }
    } else if (b < 24) {
        // ---- prep_w: W1/W2/W3 -> MFMA B-frag order, fp16 hi/lo split ----
        const int id = (b - 16) * 256 + tid;        // 0..2047
        const int lane = id & 63;
        const int m = lane & 15, quad = lane >> 4;
        const float* W; _Float16 *dh, *dl; int frag;
        if (id < 1024)      { W = W1; dh = w1h; dl = w1l; frag = id >> 6; }
        else if (id < 1536) { W = W2; dh = w2h; dl = w2l; frag = (id - 1024) >> 6; }
        else                { W = W3; dh = w3h; dl = w3l; frag = (id - 1536) >> 6; }
        const int kc = frag >> 2, nt = frag & 3;
        half8 hi, lo;
        #pragma unroll
        for (int j = 0; j < 8; ++j) {
            const float v = W[(long)(kc * 32 + quad * 8 + j) * 64 + nt * 16 + m];
            hi[j] = (_Float16)v;
            lo[j] = (_Float16)(v - (float)hi[j]);
        }
        const long dst = (long)(frag * 64 + lane) * 8;
        *(half8*)(dh + dst) = hi;
        *(half8*)(dl + dst) = lo;
    } else {
        // ---- e2 + zero_loss ----
        if (b == 24 && tid == 0) *loss = 0.0f;
        const int c = (b - 24) * 256 + tid;
        const float4* row = (const float4*)(cb + (long)c * OUT_DIM);
        float s = 0.0f;
        #pragma unroll
        for (int mq = 0; mq < 16; ++mq) {
            const float4 v = row[mq];
            s += v.x * v.x + v.y * v.y + v.z * v.z + v.w * v.w;
        }
        e2[c] = s;
    }
}

#define MFMA16(A, B, C) __builtin_amdgcn_mfma_f32_16x16x32_f16(A, B, C, 0, 0, 0)

__device__ __forceinline__ void split16(const float* xs, half8& h, half8& l) {
    #pragma unroll
    for (int j = 0; j < 8; ++j) {
        h[j] = (_Float16)xs[j];
        l[j] = (_Float16)(xs[j] - (float)h[j]);
    }
}

// exact fp32 distance update (R2/R3 proven numerics); xr may be LDS.
__device__ __forceinline__ void exact_upd(
    const float* xr, const float* __restrict__ cb,
    const float* __restrict__ e2, int n, float& bd, int& bi)
{
    const float4* xp = (const float4*)xr;
    const float4* cp = (const float4*)(cb + (long)n * OUT_DIM);
    float a0 = 0.0f, a1 = 0.0f;
    #pragma unroll
    for (int m = 0; m < 16; ++m) {
        const float4 xv = xp[m], cv = cp[m];
        a0 = fmaf(xv.x, cv.x, a0); a1 = fmaf(xv.y, cv.y, a1);
        a0 = fmaf(xv.z, cv.z, a0); a1 = fmaf(xv.w, cv.w, a1);
    }
    const float ex = fmaf(-2.0f, a0 + a1, e2[n]);
    if (ex < bd || (ex == bd && n < bi)) { bd = ex; bi = n; }
}

// ---------------- FUSED: MLP (wave-local, x -> LDS) + VQ (LDS-staged cb) ----
__global__ __launch_bounds__(256, 4) void fused_mlp_vq(
    const float* __restrict__ obs,
    const float* __restrict__ b1, const float* __restrict__ b2,
    const float* __restrict__ b3,
    const _Float16* __restrict__ w1h, const _Float16* __restrict__ w1l,
    const _Float16* __restrict__ w2h, const _Float16* __restrict__ w2l,
    const _Float16* __restrict__ w3h, const _Float16* __restrict__ w3l,
    const float* __restrict__ cb,
    const _Float16* __restrict__ cbhp,
    const float* __restrict__ e2,
    float* __restrict__ msg,        // out only: quantize
    float* __restrict__ idx_out,
    float* __restrict__ loss_out)
{
    __shared__ float hbuf[64 * 68];         // mlp scratch, then x[64][64] @68
    __shared__ _Float16 stg[2][2048];       // 2-tile phase double buffer (8 KB)
    __shared__ float best_d_s[4][16][16];   // [wave][pt][col]
    __shared__ int   best_i_s[4][16][16];
    __shared__ int   cand_pc[CAND_CAP];     // (p_local<<16) | code
    __shared__ float cand_d[CAND_CAP];
    __shared__ int   cand_cnt;
    __shared__ int   idx_sh[64];
    __shared__ float wred[4];

    const int t = threadIdx.x, lane = t & 63, w = t >> 6;
    const int m = lane & 15, quad = lane >> 4;
    const long base = (long)blockIdx.x * 64;
    const int row0 = w * 16 + quad * 4;         // C-layout write rows (+r)
    const int arow_l = w * 16 + m;              // A-layout read row

    if (t == 0) cand_cnt = 0;

    // ================= MLP phase (R13-verbatim, wave-local) =================
    {
        float bb1[4], bb2[4], bb3[4];
        #pragma unroll
        for (int nt = 0; nt < 4; ++nt) {
            bb1[nt] = b1[nt * 16 + m];
            bb2[nt] = b2[nt * 16 + m];
            bb3[nt] = b3[nt * 16 + m];
        }

        const float* arow = obs + (base + w * 16 + m) * IN_DIM;
        half8 a1h[4], a1l[4];
        #pragma unroll
        for (int kc = 0; kc < 4; ++kc) {
            const float4 va = *(const float4*)(arow + kc * 32 + quad * 8);
            const float4 vb = *(const float4*)(arow + kc * 32 + quad * 8 + 4);
            const float xs[8] = {va.x, va.y, va.z, va.w, vb.x, vb.y, vb.z, vb.w};
            split16(xs, a1h[kc], a1l[kc]);
        }

        // layer 1
        #pragma unroll
        for (int nt = 0; nt < 4; ++nt) {
            f32x4 acc = {0.0f, 0.0f, 0.0f, 0.0f};
            #pragma unroll
            for (int kc = 0; kc < 4; ++kc) {
                const long fo = (long)((kc * 4 + nt) * 64 + lane) * 8;
                const half8 wh = *(const half8*)(w1h + fo);
                const half8 wl = *(const half8*)(w1l + fo);
                acc = MFMA16(a1h[kc], wh, acc);
                acc = MFMA16(a1l[kc], wh, acc);
                acc = MFMA16(a1h[kc], wl, acc);
            }
            #pragma unroll
            for (int r = 0; r < 4; ++r) {
                const float v = acc[r] + bb1[nt];
                hbuf[(row0 + r) * 68 + nt * 16 + m] = v > 0.0f ? v : 0.0f;
            }
        }

        // layer 2
        half8 a2h[2], a2l[2];
        #pragma unroll
        for (int kc = 0; kc < 2; ++kc) {
            const float4 va = *(const float4*)&hbuf[arow_l * 68 + kc * 32 + quad * 8];
            const float4 vb = *(const float4*)&hbuf[arow_l * 68 + kc * 32 + quad * 8 + 4];
            const float xs[8] = {va.x, va.y, va.z, va.w, vb.x, vb.y, vb.z, vb.w};
            split16(xs, a2h[kc], a2l[kc]);
        }
        #pragma unroll
        for (int nt = 0; nt < 4; ++nt) {
            f32x4 acc = {0.0f, 0.0f, 0.0f, 0.0f};
            #pragma unroll
            for (int kc = 0; kc < 2; ++kc) {
                const long fo = (long)((kc * 4 + nt) * 64 + lane) * 8;
                const half8 wh = *(const half8*)(w2h + fo);
                const half8 wl = *(const half8*)(w2l + fo);
                acc = MFMA16(a2h[kc], wh, acc);
                acc = MFMA16(a2l[kc], wh, acc);
                acc = MFMA16(a2h[kc], wl, acc);
            }
            #pragma unroll
            for (int r = 0; r < 4; ++r) {
                const float v = acc[r] + bb2[nt];
                hbuf[(row0 + r) * 68 + nt * 16 + m] = v > 0.0f ? v : 0.0f;
            }
        }

        // layer 3 -> x rows in hbuf
        half8 a3h[2], a3l[2];
        #pragma unroll
        for (int kc = 0; kc < 2; ++kc) {
            const float4 va = *(const float4*)&hbuf[arow_l * 68 + kc * 32 + quad * 8];
            const float4 vb = *(const float4*)&hbuf[arow_l * 68 + kc * 32 + quad * 8 + 4];
            const float xs[8] = {va.x, va.y, va.z, va.w, vb.x, vb.y, vb.z, vb.w};
            split16(xs, a3h[kc], a3l[kc]);
        }
        #pragma unroll
        for (int nt = 0; nt < 4; ++nt) {
            f32x4 acc = {0.0f, 0.0f, 0.0f, 0.0f};
            #pragma unroll
            for (int kc = 0; kc < 2; ++kc) {
                const long fo = (long)((kc * 4 + nt) * 64 + lane) * 8;
                const half8 wh = *(const half8*)(w3h + fo);
                const half8 wl = *(const half8*)(w3l + fo);
                acc = MFMA16(a3h[kc], wh, acc);
                acc = MFMA16(a3l[kc], wh, acc);
                acc = MFMA16(a3h[kc], wl, acc);
            }
            #pragma unroll
            for (int r = 0; r < 4; ++r)
                hbuf[(row0 + r) * 68 + nt * 16 + m] = acc[r] + bb3[nt];
        }
    }

    // ======== VQ phase: fp16 single-product screen, LDS-staged codebook =====
    // prologue stage: phase 0 (tiles 0-1, 4 KB); wave w loads 1 KB chunk w
    gld16(&stg[0][w * 512], cbhp + (long)w * 512 + (long)lane * 8);

    // A-frags: x[point = w*16 + m][k = quad*8 + j] from LDS (wave-local rows).
    const float* xrow = &hbuf[(w * 16 + m) * 68];
    half8 a0h, a1h;
    {
        const float4 xa = *(const float4*)(xrow + quad * 8);
        const float4 xb = *(const float4*)(xrow + quad * 8 + 4);
        const float4 xc = *(const float4*)(xrow + 32 + quad * 8);
        const float4 xd = *(const float4*)(xrow + 32 + quad * 8 + 4);
        const float x0[8] = {xa.x, xa.y, xa.z, xa.w, xb.x, xb.y, xb.z, xb.w};
        const float x1[8] = {xc.x, xc.y, xc.z, xc.w, xd.x, xd.y, xd.z, xd.w};
        #pragma unroll
        for (int j = 0; j < 8; ++j) {
            a0h[j] = (_Float16)x0[j];
            a1h[j] = (_Float16)x1[j];
        }
    }
    __syncthreads();   // drains stage-0 vmcnt; cand_cnt + hbuf visible

    float bd[4] = {3.4e38f, 3.4e38f, 3.4e38f, 3.4e38f};
    int   bi[4] = {0, 0, 0, 0};

    // 64 phases x 2 tiles; stage next phase before computing current
    for (int ph = 0; ph < 64; ++ph) {
        const int cur = ph & 1, nb = cur ^ 1;
        if (ph < 63)
            gld16(&stg[nb][w * 512],
                  cbhp + (long)(ph + 1) * 2048 + (long)w * 512 + (long)lane * 8);

        #pragma unroll
        for (int i = 0; i < 2; ++i) {
            const int tile = ph * 2 + i;
            const half8 th0 = *(const half8*)&stg[cur][i * 1024 + lane * 8];
            const half8 th1 = *(const half8*)&stg[cur][i * 1024 + 512 + lane * 8];
            const float e2v = e2[tile * 16 + m];

            f32x4 acc0 = {0.0f, 0.0f, 0.0f, 0.0f};
            f32x4 acc1 = {0.0f, 0.0f, 0.0f, 0.0f};
            acc0 = MFMA16(a0h, th0, acc0);
            acc1 = MFMA16(a1h, th1, acc1);

            const int code = tile * 16 + m;
            bool pushm[4]; float pv[4]; int pi[4];
            #pragma unroll
            for (int r = 0; r < 4; ++r) {
                const float d = fmaf(-2.0f, acc0[r] + acc1[r], e2v);
                const bool lt = d < bd[r];
                // push iff loser within MARG of winner (== R3's two push cases)
                pushm[r] = (d < bd[r] + MARG) & (bd[r] < d + MARG);
                pv[r] = lt ? bd[r] : d;          // loser's distance
                pi[r] = lt ? bi[r] : code;       // loser's code
                bd[r] = lt ? d : bd[r];
                bi[r] = lt ? code : bi[r];
            }
            if (__any((int)(pushm[0] | pushm[1] | pushm[2] | pushm[3]))) {
                #pragma unroll
                for (int r = 0; r < 4; ++r) {
                    if (pushm[r]) {
                        const int slot = atomicAdd(&cand_cnt, 1);
                        if (slot < CAND_CAP) {
                            cand_pc[slot] = ((w * 16 + quad * 4 + r) << 16) | pi[r];
                            cand_d[slot]  = pv[r];
                        }
                    }
                }
            }
        }
        __syncthreads();    // drains next-phase stage; protects buffer swap
    }

    // publish per-slot bests: point row = quad*4 + r, col = m
    #pragma unroll
    for (int r = 0; r < 4; ++r) {
        best_d_s[w][quad * 4 + r][m] = bd[r];
        best_i_s[w][quad * 4 + r][m] = bi[r];
    }
    __syncthreads();

    // exact-rescore stage: one thread per point (x read from LDS)
    if (t < 64) {
        const int p = t, ww = p >> 4, pi_ = p & 15;
        float dmin = 3.4e38f;
        #pragma unroll
        for (int c = 0; c < 16; ++c) dmin = fminf(dmin, best_d_s[ww][pi_][c]);
        const float thr = dmin + MARG;

        float fbd = 3.4e38f; int fbi = 1 << 30;
        const float* xr = &hbuf[p * 68];
        #pragma unroll
        for (int c = 0; c < 16; ++c)
            if (best_d_s[ww][pi_][c] <= thr)
                exact_upd(xr, cb, e2, best_i_s[ww][pi_][c], fbd, fbi);
        const int L = min(cand_cnt, CAND_CAP);
        for (int l = 0; l < L; ++l) {
            const int pc = cand_pc[l];
            if ((pc >> 16) == p && cand_d[l] <= thr)
                exact_upd(xr, cb, e2, pc & 0xFFFF, fbd, fbi);
        }
        idx_sh[p] = fbi;
        idx_out[base + p] = (float)fbi;
    }
    __syncthreads();

    // gather q, write msg (write-only), accumulate loss (x from LDS)
    float lsum = 0.0f;
    float4* mg = (float4*)(msg + base * OUT_DIM);
    #pragma unroll
    for (int mm = 0; mm < 4; ++mm) {
        const int v = t + 256 * mm;
        const int p = v >> 4, k4 = v & 15;
        const int code = idx_sh[p];
        const float4 q = ((const float4*)(cb + (long)code * OUT_DIM))[k4];
        const float4 xv = *(const float4*)&hbuf[p * 68 + k4 * 4];
        const float dx = q.x - xv.x, dy = q.y - xv.y;
        const float dz = q.z - xv.z, dw2 = q.w - xv.w;
        lsum += dx * dx + dy * dy + dz * dz + dw2 * dw2;
        mg[v] = q;
    }
    #pragma unroll
    for (int off = 32; off > 0; off >>= 1) lsum += __shfl_down(lsum, off, 64);
    if (lane == 0) wred[w] = lsum;
    __syncthreads();
    if (t == 0)
        atomicAdd(loss_out, (wred[0] + wred[1] + wred[2] + wred[3]) * LOSS_SCALE);
}

extern "C" void kernel_launch(void* const* d_in, const int* in_sizes, int n_in,
                              void* d_out, int out_size, void* d_ws, size_t ws_size,
                              hipStream_t stream) {
    const float* obs = (const float*)d_in[0];
    const float* W1  = (const float*)d_in[1];
    const float* b1  = (const float*)d_in[2];
    const float* W2  = (const float*)d_in[3];
    const float* b2  = (const float*)d_in[4];
    const float* W3  = (const float*)d_in[5];
    const float* b3  = (const float*)d_in[6];
    const float* cb  = (const float*)d_in[7];

    float* out  = (float*)d_out;
    float* msg  = out;
    float* idxf = out + MSG_ELEMS;
    float* loss = out + MSG_ELEMS + NPTS;

    char* ws = (char*)d_ws;
    float*     e2  = (float*)ws;                          // 8 KB
    _Float16*  cbh = (_Float16*)(ws + 8192);              // 256 KB (fp16 hi)
    _Float16* w1h = (_Float16*)(ws + 532480);             // 16 KB
    _Float16* w1l = (_Float16*)(ws + 548864);             // 16 KB
    _Float16* w2h = (_Float16*)(ws + 565248);             // 8 KB
    _Float16* w2l = (_Float16*)(ws + 573440);             // 8 KB
    _Float16* w3h = (_Float16*)(ws + 581632);             // 8 KB
    _Float16* w3l = (_Float16*)(ws + 589824);             // 8 KB

    prep_all<<<32, 256, 0, stream>>>(cb, W1, W2, W3, e2, cbh,
                                     w1h, w1l, w2h, w2l, w3h, w3l, loss);
    fused_mlp_vq<<<NPTS / 64, 256, 0, stream>>>(
        obs, b1, b2, b3, w1h, w1l, w2h, w2l, w3h, w3l,
        cb, cbh, e2, msg, idxf, loss);
}

// Round 7
// 167.646 us; speedup vs baseline: 1.2533x; 1.2533x over previous
//
#include <hip/hip_runtime.h>

// VQSpeaker: obs[32,2048,128] -> 3-layer MLP -> x[65536,64] -> VQ argmin over
// codebook[2048,64] -> (msg = codebook[idx], idx, cmt_loss).
//
// Round 15: LDS-RESIDENT codebook quarters, barrier-minimal scan.
//   R14 lesson (regressed): 64 per-phase barriers with 2 tiles/phase = m233
//   stall mode. Now: 512-thr blocks (8 waves, 128 pts), grid 512 = 2/CU;
//   stage 64 KB (512 codes) once -> scan 32 tiles barrier-free -> repeat x4.
//   ~10 barriers total; inner loop has ZERO global loads (ds_read + MFMA +
//   screen only). Second block/CU covers stage latency.
//   x lives in msg (R10-proven); hbuf (35 KB) overlays the 64 KB stage region.
//   Winner per point via 16-lane __shfl_xor argmin butterfly (replaces
//   best_*_s LDS); near-ties pushed to cand list (no dist stored); exact
//   fp32 rescore parallelized over all 512 threads via packed u64 atomicMin
//   (ordered-dist<<32 | code; min = smaller dist, tie -> smaller code, exactly
//   the reference argmin semantics). Winner rescored unconditionally ->
//   cand overflow degrades exactly like R3. Screen invariant unchanged:
//   every code within MARG of the screened min is exactly rescored
//   (fp16 screen error ~0.20 < MARG/2 = 0.25, R13-proven).
//
// d_out layout (float32): msg[4194304] | idx[65536] (as float) | loss[1]
// d_ws: e2[2048] | cbh fp16 256KB | w1h/w1l 16KB ea | w2h/w2l/w3h/w3l 8KB ea

#define NPTS    65536
#define IN_DIM  128
#define HID     64
#define OUT_DIM 64
#define CB_N    2048
#define MSG_ELEMS (NPTS * OUT_DIM)
#define LOSS_SCALE (1.0f / 4194304.0f)
#define MARG 0.5f          // R3-proven screening margin
#define CAND_CAP 1024      // 8 per point, same ratio as R3's 512/64
#define BPTS 128           // points per block (8 waves x 16)
#define NTHR 512

typedef __attribute__((ext_vector_type(8))) short short8;
typedef _Float16 half8 __attribute__((ext_vector_type(8)));
typedef __attribute__((ext_vector_type(4))) float f32x4;
typedef unsigned int u32;
typedef unsigned long long u64;

// async global->LDS, 16B/lane: LDS dest = wave-uniform base + lane*16
__device__ __forceinline__ void gld16(void* lds_base, const void* gsrc) {
    __builtin_amdgcn_global_load_lds(
        (const __attribute__((address_space(1))) u32*)gsrc,
        (__attribute__((address_space(3))) u32*)lds_base, 16, 0, 0);
}

// ---- merged prep: blocks 0-15 prep_cb, 16-23 prep_w, 24-31 e2 (+loss=0) ----
__global__ __launch_bounds__(256) void prep_all(
    const float* __restrict__ cb,
    const float* __restrict__ W1, const float* __restrict__ W2,
    const float* __restrict__ W3,
    float* __restrict__ e2,
    _Float16* __restrict__ cbh,
    _Float16* __restrict__ w1h, _Float16* __restrict__ w1l,
    _Float16* __restrict__ w2h, _Float16* __restrict__ w2l,
    _Float16* __restrict__ w3h, _Float16* __restrict__ w3l,
    float* __restrict__ loss)
{
    const int b = blockIdx.x, tid = threadIdx.x;
    if (b < 16) {
        // ---- prep_cb: codebook -> MFMA B-frag order, fp16 ----
        const int id = b * 256 + tid;               // 0..4095: (code n, half h)
        const int n = id >> 1, h = id & 1;
        const int t = n >> 4, l15 = n & 15;
        const float* src = cb + (long)n * OUT_DIM + h * 32;
        #pragma unroll
        for (int quad = 0; quad < 4; ++quad) {
            half8 hi;
            #pragma unroll
            for (int j = 0; j < 8; ++j)
                hi[j] = (_Float16)src[quad * 8 + j];
            const long dst = ((long)(t * 2 + h) * 64 + quad * 16 + l15) * 8;
            *(half8*)(cbh + dst) = hi;
        }
    } else if (b < 24) {
        // ---- prep_w: W1/W2/W3 -> MFMA B-frag order, fp16 hi/lo split ----
        const int id = (b - 16) * 256 + tid;        // 0..2047
        const int lane = id & 63;
        const int m = lane & 15, quad = lane >> 4;
        const float* W; _Float16 *dh, *dl; int frag;
        if (id < 1024)      { W = W1; dh = w1h; dl = w1l; frag = id >> 6; }
        else if (id < 1536) { W = W2; dh = w2h; dl = w2l; frag = (id - 1024) >> 6; }
        else                { W = W3; dh = w3h; dl = w3l; frag = (id - 1536) >> 6; }
        const int kc = frag >> 2, nt = frag & 3;
        half8 hi, lo;
        #pragma unroll
        for (int j = 0; j < 8; ++j) {
            const float v = W[(long)(kc * 32 + quad * 8 + j) * 64 + nt * 16 + m];
            hi[j] = (_Float16)v;
            lo[j] = (_Float16)(v - (float)hi[j]);
        }
        const long dst = (long)(frag * 64 + lane) * 8;
        *(half8*)(dh + dst) = hi;
        *(half8*)(dl + dst) = lo;
    } else {
        // ---- e2 + zero_loss ----
        if (b == 24 && tid == 0) *loss = 0.0f;
        const int c = (b - 24) * 256 + tid;
        const float4* row = (const float4*)(cb + (long)c * OUT_DIM);
        float s = 0.0f;
        #pragma unroll
        for (int mq = 0; mq < 16; ++mq) {
            const float4 v = row[mq];
            s += v.x * v.x + v.y * v.y + v.z * v.z + v.w * v.w;
        }
        e2[c] = s;
    }
}

#define MFMA16(A, B, C) __builtin_amdgcn_mfma_f32_16x16x32_f16(A, B, C, 0, 0, 0)

__device__ __forceinline__ void split16(const float* xs, half8& h, half8& l) {
    #pragma unroll
    for (int j = 0; j < 8; ++j) {
        h[j] = (_Float16)xs[j];
        l[j] = (_Float16)(xs[j] - (float)h[j]);
    }
}

// packed rescore key: (total-order fp32 dist << 32) | code.
// min over keys == (min dist, tie -> min code) == reference argmin semantics.
__device__ __forceinline__ u64 packkey(float d, int n) {
    u32 ub = __float_as_uint(d);
    ub = (ub & 0x80000000u) ? ~ub : (ub | 0x80000000u);
    return ((u64)ub << 32) | (u32)n;
}

// exact fp32 distance (R2/R3-proven pairing: two partial sums, fmaf(-2,s,e2))
__device__ __forceinline__ float exdist(
    const float* __restrict__ xr, const float* __restrict__ cbrow, float e2v)
{
    const float4* xp = (const float4*)xr;
    const float4* cp = (const float4*)cbrow;
    float a0 = 0.0f, a1 = 0.0f;
    #pragma unroll
    for (int mq = 0; mq < 16; ++mq) {
        const float4 xv = xp[mq], cv = cp[mq];
        a0 = fmaf(xv.x, cv.x, a0); a1 = fmaf(xv.y, cv.y, a1);
        a0 = fmaf(xv.z, cv.z, a0); a1 = fmaf(xv.w, cv.w, a1);
    }
    return fmaf(-2.0f, a0 + a1, e2v);
}

// ---------------- FUSED: MLP + VQ with LDS-resident codebook quarters ------
__global__ __launch_bounds__(NTHR, 4) void fused_mlp_vq(
    const float* __restrict__ obs,
    const float* __restrict__ b1, const float* __restrict__ b2,
    const float* __restrict__ b3,
    const _Float16* __restrict__ w1h, const _Float16* __restrict__ w1l,
    const _Float16* __restrict__ w2h, const _Float16* __restrict__ w2l,
    const _Float16* __restrict__ w3h, const _Float16* __restrict__ w3l,
    const float* __restrict__ cb,
    const _Float16* __restrict__ cbhp,
    const float* __restrict__ e2,
    float* __restrict__ msg,        // staging: x, then overwritten with q
    float* __restrict__ idx_out,
    float* __restrict__ loss_out)
{
    // region0: MLP hbuf[128][68] (34.8 KB) OVERLAID by 64 KB codebook quarter
    __shared__ __align__(16) char smem[65536];
    __shared__ float e2s[CB_N];             // 8 KB
    __shared__ int   cand_pc[CAND_CAP];     // 4 KB: (p_local<<16) | code
    __shared__ u64   keys[BPTS];            // 1 KB packed rescore keys
    __shared__ int   win_sh[BPTS];          // screened winners
    __shared__ int   idx_sh[BPTS];
    __shared__ float wred[NTHR / 64];
    __shared__ int   cand_cnt;

    const int t = threadIdx.x, lane = t & 63, w = t >> 6;
    const int m = lane & 15, quad = lane >> 4;
    const long base = (long)blockIdx.x * BPTS;
    float* hbuf = (float*)smem;
    const int row0 = w * 16 + quad * 4;         // C-layout write rows (+r)
    const int arow_l = w * 16 + m;              // A-layout read row

    if (t == 0) cand_cnt = 0;
    if (t < BPTS) keys[t] = ~0ULL;
    ((float4*)e2s)[t] = ((const float4*)e2)[t];   // 512 x 16B = full table

    // ================= MLP phase (R13-verbatim, wave-local, 8 waves) ========
    {
        float bb1[4], bb2[4], bb3[4];
        #pragma unroll
        for (int nt = 0; nt < 4; ++nt) {
            bb1[nt] = b1[nt * 16 + m];
            bb2[nt] = b2[nt * 16 + m];
            bb3[nt] = b3[nt * 16 + m];
        }

        const float* arow = obs + (base + w * 16 + m) * IN_DIM;
        half8 a1h[4], a1l[4];
        #pragma unroll
        for (int kc = 0; kc < 4; ++kc) {
            const float4 va = *(const float4*)(arow + kc * 32 + quad * 8);
            const float4 vb = *(const float4*)(arow + kc * 32 + quad * 8 + 4);
            const float xs[8] = {va.x, va.y, va.z, va.w, vb.x, vb.y, vb.z, vb.w};
            split16(xs, a1h[kc], a1l[kc]);
        }

        // layer 1
        #pragma unroll
        for (int nt = 0; nt < 4; ++nt) {
            f32x4 acc = {0.0f, 0.0f, 0.0f, 0.0f};
            #pragma unroll
            for (int kc = 0; kc < 4; ++kc) {
                const long fo = (long)((kc * 4 + nt) * 64 + lane) * 8;
                const half8 wh = *(const half8*)(w1h + fo);
                const half8 wl = *(const half8*)(w1l + fo);
                acc = MFMA16(a1h[kc], wh, acc);
                acc = MFMA16(a1l[kc], wh, acc);
                acc = MFMA16(a1h[kc], wl, acc);
            }
            #pragma unroll
            for (int r = 0; r < 4; ++r) {
                const float v = acc[r] + bb1[nt];
                hbuf[(row0 + r) * 68 + nt * 16 + m] = v > 0.0f ? v : 0.0f;
            }
        }

        // layer 2
        half8 a2h[2], a2l[2];
        #pragma unroll
        for (int kc = 0; kc < 2; ++kc) {
            const float4 va = *(const float4*)&hbuf[arow_l * 68 + kc * 32 + quad * 8];
            const float4 vb = *(const float4*)&hbuf[arow_l * 68 + kc * 32 + quad * 8 + 4];
            const float xs[8] = {va.x, va.y, va.z, va.w, vb.x, vb.y, vb.z, vb.w};
            split16(xs, a2h[kc], a2l[kc]);
        }
        #pragma unroll
        for (int nt = 0; nt < 4; ++nt) {
            f32x4 acc = {0.0f, 0.0f, 0.0f, 0.0f};
            #pragma unroll
            for (int kc = 0; kc < 2; ++kc) {
                const long fo = (long)((kc * 4 + nt) * 64 + lane) * 8;
                const half8 wh = *(const half8*)(w2h + fo);
                const half8 wl = *(const half8*)(w2l + fo);
                acc = MFMA16(a2h[kc], wh, acc);
                acc = MFMA16(a2l[kc], wh, acc);
                acc = MFMA16(a2h[kc], wl, acc);
            }
            #pragma unroll
            for (int r = 0; r < 4; ++r) {
                const float v = acc[r] + bb2[nt];
                hbuf[(row0 + r) * 68 + nt * 16 + m] = v > 0.0f ? v : 0.0f;
            }
        }

        // layer 3 -> x rows in hbuf
        half8 a3h[2], a3l[2];
        #pragma unroll
        for (int kc = 0; kc < 2; ++kc) {
            const float4 va = *(const float4*)&hbuf[arow_l * 68 + kc * 32 + quad * 8];
            const float4 vb = *(const float4*)&hbuf[arow_l * 68 + kc * 32 + quad * 8 + 4];
            const float xs[8] = {va.x, va.y, va.z, va.w, vb.x, vb.y, vb.z, vb.w};
            split16(xs, a3h[kc], a3l[kc]);
        }
        #pragma unroll
        for (int nt = 0; nt < 4; ++nt) {
            f32x4 acc = {0.0f, 0.0f, 0.0f, 0.0f};
            #pragma unroll
            for (int kc = 0; kc < 2; ++kc) {
                const long fo = (long)((kc * 4 + nt) * 64 + lane) * 8;
                const half8 wh = *(const half8*)(w3h + fo);
                const half8 wl = *(const half8*)(w3l + fo);
                acc = MFMA16(a3h[kc], wh, acc);
                acc = MFMA16(a3l[kc], wh, acc);
                acc = MFMA16(a3h[kc], wl, acc);
            }
            #pragma unroll
            for (int r = 0; r < 4; ++r)
                hbuf[(row0 + r) * 68 + nt * 16 + m] = acc[r] + bb3[nt];
        }
    }

    // A-frags (wave-local hbuf reads, before overwrite): fp16 screen operands
    half8 a0h, a1h;
    {
        const float* xrow = &hbuf[(w * 16 + m) * 68];
        const float4 xa = *(const float4*)(xrow + quad * 8);
        const float4 xb = *(const float4*)(xrow + quad * 8 + 4);
        const float4 xc = *(const float4*)(xrow + 32 + quad * 8);
        const float4 xd = *(const float4*)(xrow + 32 + quad * 8 + 4);
        const float x0[8] = {xa.x, xa.y, xa.z, xa.w, xb.x, xb.y, xb.z, xb.w};
        const float x1[8] = {xc.x, xc.y, xc.z, xc.w, xd.x, xd.y, xd.z, xd.w};
        #pragma unroll
        for (int j = 0; j < 8; ++j) {
            a0h[j] = (_Float16)x0[j];
            a1h[j] = (_Float16)x1[j];
        }
    }
    __syncthreads();    // all hbuf rows final (cross-wave reads next)

    // x -> msg (coalesced; rescore + loss read it back; then overwritten w/ q)
    {
        float4* mg = (float4*)(msg + base * OUT_DIM);
        #pragma unroll
        for (int mm = 0; mm < 4; ++mm) {
            const int v = t + NTHR * mm;
            const int p = v >> 4, k4 = v & 15;
            mg[v] = *(const float4*)&hbuf[p * 68 + k4 * 4];
        }
    }
    __syncthreads();    // hbuf reads done; staging may overwrite region0

    // ========== VQ scan: 4 x (stage 64 KB quarter -> 32 barrier-free tiles) =
    float bd[4] = {3.4e38f, 3.4e38f, 3.4e38f, 3.4e38f};
    int   bi[4] = {0, 0, 0, 0};

    for (int qp = 0; qp < 4; ++qp) {
        const _Float16* cbq = cbhp + (long)qp * 32768;  // 64 KB = 32768 halves
        #pragma unroll
        for (int j = 0; j < 8; ++j)
            gld16(smem + j * 8192 + w * 1024, cbq + j * 4096 + w * 512 + lane * 8);
        __syncthreads();    // implicit vmcnt drain: quarter resident

        #pragma unroll 4
        for (int tl = 0; tl < 32; ++tl) {
            const int g = qp * 32 + tl;
            const half8 th0 = *(const half8*)(smem + tl * 2048 + lane * 16);
            const half8 th1 = *(const half8*)(smem + tl * 2048 + 1024 + lane * 16);
            const float e2v = e2s[g * 16 + m];
            f32x4 acc = {0.0f, 0.0f, 0.0f, 0.0f};
            acc = MFMA16(a0h, th0, acc);
            acc = MFMA16(a1h, th1, acc);

            const int code = g * 16 + m;
            bool pushm[4]; int pip[4];
            #pragma unroll
            for (int r = 0; r < 4; ++r) {
                const float d = fmaf(-2.0f, acc[r], e2v);
                const bool lt = d < bd[r];
                // push loser iff within MARG of winner (== R3's two cases)
                pushm[r] = (d < bd[r] + MARG) & (bd[r] < d + MARG);
                pip[r] = lt ? bi[r] : code;
                bd[r] = lt ? d : bd[r];
                bi[r] = lt ? code : bi[r];
            }
            if (__any((int)(pushm[0] | pushm[1] | pushm[2] | pushm[3]))) {
                #pragma unroll
                for (int r = 0; r < 4; ++r) {
                    if (pushm[r]) {
                        const int slot = atomicAdd(&cand_cnt, 1);
                        if (slot < CAND_CAP)
                            cand_pc[slot] = ((w * 16 + quad * 4 + r) << 16) | pip[r];
                    }
                }
            }
        }
        __syncthreads();    // scan done before next stage overwrites region0
    }

    // per-point screened winner via 16-lane argmin butterfly; near-tie pushes
    {
        float rd[4]; int ri[4];
        #pragma unroll
        for (int r = 0; r < 4; ++r) { rd[r] = bd[r]; ri[r] = bi[r]; }
        #pragma unroll
        for (int off = 1; off <= 8; off <<= 1) {
            #pragma unroll
            for (int r = 0; r < 4; ++r) {
                const float od = __shfl_xor(rd[r], off, 64);
                const int   oi = __shfl_xor(ri[r], off, 64);
                if (od < rd[r] || (od == rd[r] && oi < ri[r])) {
                    rd[r] = od; ri[r] = oi;
                }
            }
        }
        #pragma unroll
        for (int r = 0; r < 4; ++r) {
            const int pl = w * 16 + quad * 4 + r;
            if (m == 0) win_sh[pl] = ri[r];
            if (bd[r] <= rd[r] + MARG && bi[r] != ri[r]) {
                const int slot = atomicAdd(&cand_cnt, 1);
                if (slot < CAND_CAP)
                    cand_pc[slot] = (pl << 16) | bi[r];
            }
        }
    }
    __syncthreads();    // win_sh + cand list final

    // exact fp32 rescore, parallel over all threads, packed atomicMin.
    // winners rescored unconditionally (immune to cand overflow, like R3).
    {
        if (t < BPTS) {
            const int n = win_sh[t];
            const float ex = exdist(msg + (base + t) * OUT_DIM,
                                    cb + (long)n * OUT_DIM, e2s[n]);
            atomicMin(&keys[t], packkey(ex, n));
        }
        const int L = min(cand_cnt, CAND_CAP);
        for (int l = t; l < L; l += NTHR) {
            const int pc = cand_pc[l];
            const int p = pc >> 16, n = pc & 0xFFFF;
            const float ex = exdist(msg + (base + p) * OUT_DIM,
                                    cb + (long)n * OUT_DIM, e2s[n]);
            atomicMin(&keys[p], packkey(ex, n));
        }
    }
    __syncthreads();

    if (t < BPTS) {
        const int code = (int)(keys[t] & 0xFFFFFFFFu);
        idx_sh[t] = code;
        idx_out[base + t] = (float)code;
    }
    __syncthreads();

    // gather q, write msg, accumulate loss (read-x / write-q same thread+addr)
    float lsum = 0.0f;
    float4* mg = (float4*)(msg + base * OUT_DIM);
    #pragma unroll
    for (int mm = 0; mm < 4; ++mm) {
        const int v = t + NTHR * mm;
        const int p = v >> 4, k4 = v & 15;
        const int code = idx_sh[p];
        const float4 q = ((const float4*)(cb + (long)code * OUT_DIM))[k4];
        const float4 xv = mg[v];
        const float dx = q.x - xv.x, dy = q.y - xv.y;
        const float dz = q.z - xv.z, dw2 = q.w - xv.w;
        lsum += dx * dx + dy * dy + dz * dz + dw2 * dw2;
        mg[v] = q;
    }
    #pragma unroll
    for (int off = 32; off > 0; off >>= 1) lsum += __shfl_down(lsum, off, 64);
    if (lane == 0) wred[w] = lsum;
    __syncthreads();
    if (t == 0) {
        float s = 0.0f;
        #pragma unroll
        for (int i = 0; i < NTHR / 64; ++i) s += wred[i];
        atomicAdd(loss_out, s * LOSS_SCALE);
    }
}

extern "C" void kernel_launch(void* const* d_in, const int* in_sizes, int n_in,
                              void* d_out, int out_size, void* d_ws, size_t ws_size,
                              hipStream_t stream) {
    const float* obs = (const float*)d_in[0];
    const float* W1  = (const float*)d_in[1];
    const float* b1  = (const float*)d_in[2];
    const float* W2  = (const float*)d_in[3];
    const float* b2  = (const float*)d_in[4];
    const float* W3  = (const float*)d_in[5];
    const float* b3  = (const float*)d_in[6];
    const float* cb  = (const float*)d_in[7];

    float* out  = (float*)d_out;
    float* msg  = out;
    float* idxf = out + MSG_ELEMS;
    float* loss = out + MSG_ELEMS + NPTS;

    char* ws = (char*)d_ws;
    float*     e2  = (float*)ws;                          // 8 KB
    _Float16*  cbh = (_Float16*)(ws + 8192);              // 256 KB (fp16)
    _Float16* w1h = (_Float16*)(ws + 532480);             // 16 KB
    _Float16* w1l = (_Float16*)(ws + 548864);             // 16 KB
    _Float16* w2h = (_Float16*)(ws + 565248);             // 8 KB
    _Float16* w2l = (_Float16*)(ws + 573440);             // 8 KB
    _Float16* w3h = (_Float16*)(ws + 581632);             // 8 KB
    _Float16* w3l = (_Float16*)(ws + 589824);             // 8 KB

    prep_all<<<32, 256, 0, stream>>>(cb, W1, W2, W3, e2, cbh,
                                     w1h, w1l, w2h, w2l, w3h, w3l, loss);
    fused_mlp_vq<<<NPTS / BPTS, NTHR, 0, stream>>>(
        obs, b1, b2, b3, w1h, w1l, w2h, w2l, w3h, w3l,
        cb, cbh, e2, msg, idxf, loss);
}

// Round 8
// 165.701 us; speedup vs baseline: 1.2681x; 1.0117x over previous
//
#include <hip/hip_runtime.h>

// VQSpeaker: obs[32,2048,128] -> 3-layer MLP -> x[65536,64] -> VQ argmin over
// codebook[2048,64] -> (msg = codebook[idx], idx, cmt_loss).
//
// Round 16: attack the ~70us of non-fused time + scan micro-trims.
//   R15 analysis: total-minus-fused has been ~72-77us for 5 rounds; launches
//   are ~2us each, so prep_all (32 blocks = 12% of GPU, serial per-thread
//   loops) is the bulk. Now 80 blocks: prep_cb split 4-ways (64 blocks, one
//   (code,half,quad) per thread), prep_w 8, e2+loss 8. Outputs bit-identical.
//   Fused scan micro: pushm via |d-bd|<MARG (2 VALU, identical semantics),
//   s_setprio(1) around the MFMA pair (T5: free-running waves regime).
//   Everything else R15-verbatim.
//
// d_out layout (float32): msg[4194304] | idx[65536] (as float) | loss[1]
// d_ws: e2[2048] | cbh fp16 256KB | w1h/w1l 16KB ea | w2h/w2l/w3h/w3l 8KB ea

#define NPTS    65536
#define IN_DIM  128
#define HID     64
#define OUT_DIM 64
#define CB_N    2048
#define MSG_ELEMS (NPTS * OUT_DIM)
#define LOSS_SCALE (1.0f / 4194304.0f)
#define MARG 0.5f          // R3-proven screening margin
#define CAND_CAP 1024      // 8 per point, same ratio as R3's 512/64
#define BPTS 128           // points per block (8 waves x 16)
#define NTHR 512

typedef __attribute__((ext_vector_type(8))) short short8;
typedef _Float16 half8 __attribute__((ext_vector_type(8)));
typedef __attribute__((ext_vector_type(4))) float f32x4;
typedef unsigned int u32;
typedef unsigned long long u64;

// async global->LDS, 16B/lane: LDS dest = wave-uniform base + lane*16
__device__ __forceinline__ void gld16(void* lds_base, const void* gsrc) {
    __builtin_amdgcn_global_load_lds(
        (const __attribute__((address_space(1))) u32*)gsrc,
        (__attribute__((address_space(3))) u32*)lds_base, 16, 0, 0);
}

// ---- merged prep, 80 blocks: 0-63 prep_cb, 64-71 prep_w, 72-79 e2(+loss) --
__global__ __launch_bounds__(256) void prep_all(
    const float* __restrict__ cb,
    const float* __restrict__ W1, const float* __restrict__ W2,
    const float* __restrict__ W3,
    float* __restrict__ e2,
    _Float16* __restrict__ cbh,
    _Float16* __restrict__ w1h, _Float16* __restrict__ w1l,
    _Float16* __restrict__ w2h, _Float16* __restrict__ w2l,
    _Float16* __restrict__ w3h, _Float16* __restrict__ w3l,
    float* __restrict__ loss)
{
    const int b = blockIdx.x, tid = threadIdx.x;
    if (b < 64) {
        // ---- prep_cb: one (code n, half h, quad) per thread ----
        const int id = b * 256 + tid;               // 0..16383
        const int n = id >> 3, h = (id >> 2) & 1, quad = id & 3;
        const int t = n >> 4, l15 = n & 15;
        const float* src = cb + (long)n * OUT_DIM + h * 32 + quad * 8;
        half8 hi;
        #pragma unroll
        for (int j = 0; j < 8; ++j)
            hi[j] = (_Float16)src[j];
        const long dst = ((long)(t * 2 + h) * 64 + quad * 16 + l15) * 8;
        *(half8*)(cbh + dst) = hi;
    } else if (b < 72) {
        // ---- prep_w: W1/W2/W3 -> MFMA B-frag order, fp16 hi/lo split ----
        const int id = (b - 64) * 256 + tid;        // 0..2047
        const int lane = id & 63;
        const int m = lane & 15, quad = lane >> 4;
        const float* W; _Float16 *dh, *dl; int frag;
        if (id < 1024)      { W = W1; dh = w1h; dl = w1l; frag = id >> 6; }
        else if (id < 1536) { W = W2; dh = w2h; dl = w2l; frag = (id - 1024) >> 6; }
        else                { W = W3; dh = w3h; dl = w3l; frag = (id - 1536) >> 6; }
        const int kc = frag >> 2, nt = frag & 3;
        half8 hi, lo;
        #pragma unroll
        for (int j = 0; j < 8; ++j) {
            const float v = W[(long)(kc * 32 + quad * 8 + j) * 64 + nt * 16 + m];
            hi[j] = (_Float16)v;
            lo[j] = (_Float16)(v - (float)hi[j]);
        }
        const long dst = (long)(frag * 64 + lane) * 8;
        *(half8*)(dh + dst) = hi;
        *(half8*)(dl + dst) = lo;
    } else {
        // ---- e2 + zero_loss ----
        if (b == 72 && tid == 0) *loss = 0.0f;
        const int c = (b - 72) * 256 + tid;
        const float4* row = (const float4*)(cb + (long)c * OUT_DIM);
        float s = 0.0f;
        #pragma unroll
        for (int mq = 0; mq < 16; ++mq) {
            const float4 v = row[mq];
            s += v.x * v.x + v.y * v.y + v.z * v.z + v.w * v.w;
        }
        e2[c] = s;
    }
}

#define MFMA16(A, B, C) __builtin_amdgcn_mfma_f32_16x16x32_f16(A, B, C, 0, 0, 0)

__device__ __forceinline__ void split16(const float* xs, half8& h, half8& l) {
    #pragma unroll
    for (int j = 0; j < 8; ++j) {
        h[j] = (_Float16)xs[j];
        l[j] = (_Float16)(xs[j] - (float)h[j]);
    }
}

// packed rescore key: (total-order fp32 dist << 32) | code.
// min over keys == (min dist, tie -> min code) == reference argmin semantics.
__device__ __forceinline__ u64 packkey(float d, int n) {
    u32 ub = __float_as_uint(d);
    ub = (ub & 0x80000000u) ? ~ub : (ub | 0x80000000u);
    return ((u64)ub << 32) | (u32)n;
}

// exact fp32 distance (R2/R3-proven pairing: two partial sums, fmaf(-2,s,e2))
__device__ __forceinline__ float exdist(
    const float* __restrict__ xr, const float* __restrict__ cbrow, float e2v)
{
    const float4* xp = (const float4*)xr;
    const float4* cp = (const float4*)cbrow;
    float a0 = 0.0f, a1 = 0.0f;
    #pragma unroll
    for (int mq = 0; mq < 16; ++mq) {
        const float4 xv = xp[mq], cv = cp[mq];
        a0 = fmaf(xv.x, cv.x, a0); a1 = fmaf(xv.y, cv.y, a1);
        a0 = fmaf(xv.z, cv.z, a0); a1 = fmaf(xv.w, cv.w, a1);
    }
    return fmaf(-2.0f, a0 + a1, e2v);
}

// ---------------- FUSED: MLP + VQ with LDS-resident codebook quarters ------
__global__ __launch_bounds__(NTHR, 4) void fused_mlp_vq(
    const float* __restrict__ obs,
    const float* __restrict__ b1, const float* __restrict__ b2,
    const float* __restrict__ b3,
    const _Float16* __restrict__ w1h, const _Float16* __restrict__ w1l,
    const _Float16* __restrict__ w2h, const _Float16* __restrict__ w2l,
    const _Float16* __restrict__ w3h, const _Float16* __restrict__ w3l,
    const float* __restrict__ cb,
    const _Float16* __restrict__ cbhp,
    const float* __restrict__ e2,
    float* __restrict__ msg,        // staging: x, then overwritten with q
    float* __restrict__ idx_out,
    float* __restrict__ loss_out)
{
    // region0: MLP hbuf[128][68] (34.8 KB) OVERLAID by 64 KB codebook quarter
    __shared__ __align__(16) char smem[65536];
    __shared__ float e2s[CB_N];             // 8 KB
    __shared__ int   cand_pc[CAND_CAP];     // 4 KB: (p_local<<16) | code
    __shared__ u64   keys[BPTS];            // 1 KB packed rescore keys
    __shared__ int   win_sh[BPTS];          // screened winners
    __shared__ int   idx_sh[BPTS];
    __shared__ float wred[NTHR / 64];
    __shared__ int   cand_cnt;

    const int t = threadIdx.x, lane = t & 63, w = t >> 6;
    const int m = lane & 15, quad = lane >> 4;
    const long base = (long)blockIdx.x * BPTS;
    float* hbuf = (float*)smem;
    const int row0 = w * 16 + quad * 4;         // C-layout write rows (+r)
    const int arow_l = w * 16 + m;              // A-layout read row

    if (t == 0) cand_cnt = 0;
    if (t < BPTS) keys[t] = ~0ULL;
    ((float4*)e2s)[t] = ((const float4*)e2)[t];   // 512 x 16B = full table

    // ================= MLP phase (R13-verbatim, wave-local, 8 waves) ========
    {
        float bb1[4], bb2[4], bb3[4];
        #pragma unroll
        for (int nt = 0; nt < 4; ++nt) {
            bb1[nt] = b1[nt * 16 + m];
            bb2[nt] = b2[nt * 16 + m];
            bb3[nt] = b3[nt * 16 + m];
        }

        const float* arow = obs + (base + w * 16 + m) * IN_DIM;
        half8 a1h[4], a1l[4];
        #pragma unroll
        for (int kc = 0; kc < 4; ++kc) {
            const float4 va = *(const float4*)(arow + kc * 32 + quad * 8);
            const float4 vb = *(const float4*)(arow + kc * 32 + quad * 8 + 4);
            const float xs[8] = {va.x, va.y, va.z, va.w, vb.x, vb.y, vb.z, vb.w};
            split16(xs, a1h[kc], a1l[kc]);
        }

        // layer 1
        #pragma unroll
        for (int nt = 0; nt < 4; ++nt) {
            f32x4 acc = {0.0f, 0.0f, 0.0f, 0.0f};
            #pragma unroll
            for (int kc = 0; kc < 4; ++kc) {
                const long fo = (long)((kc * 4 + nt) * 64 + lane) * 8;
                const half8 wh = *(const half8*)(w1h + fo);
                const half8 wl = *(const half8*)(w1l + fo);
                acc = MFMA16(a1h[kc], wh, acc);
                acc = MFMA16(a1l[kc], wh, acc);
                acc = MFMA16(a1h[kc], wl, acc);
            }
            #pragma unroll
            for (int r = 0; r < 4; ++r) {
                const float v = acc[r] + bb1[nt];
                hbuf[(row0 + r) * 68 + nt * 16 + m] = v > 0.0f ? v : 0.0f;
            }
        }

        // layer 2
        half8 a2h[2], a2l[2];
        #pragma unroll
        for (int kc = 0; kc < 2; ++kc) {
            const float4 va = *(const float4*)&hbuf[arow_l * 68 + kc * 32 + quad * 8];
            const float4 vb = *(const float4*)&hbuf[arow_l * 68 + kc * 32 + quad * 8 + 4];
            const float xs[8] = {va.x, va.y, va.z, va.w, vb.x, vb.y, vb.z, vb.w};
            split16(xs, a2h[kc], a2l[kc]);
        }
        #pragma unroll
        for (int nt = 0; nt < 4; ++nt) {
            f32x4 acc = {0.0f, 0.0f, 0.0f, 0.0f};
            #pragma unroll
            for (int kc = 0; kc < 2; ++kc) {
                const long fo = (long)((kc * 4 + nt) * 64 + lane) * 8;
                const half8 wh = *(const half8*)(w2h + fo);
                const half8 wl = *(const half8*)(w2l + fo);
                acc = MFMA16(a2h[kc], wh, acc);
                acc = MFMA16(a2l[kc], wh, acc);
                acc = MFMA16(a2h[kc], wl, acc);
            }
            #pragma unroll
            for (int r = 0; r < 4; ++r) {
                const float v = acc[r] + bb2[nt];
                hbuf[(row0 + r) * 68 + nt * 16 + m] = v > 0.0f ? v : 0.0f;
            }
        }

        // layer 3 -> x rows in hbuf
        half8 a3h[2], a3l[2];
        #pragma unroll
        for (int kc = 0; kc < 2; ++kc) {
            const float4 va = *(const float4*)&hbuf[arow_l * 68 + kc * 32 + quad * 8];
            const float4 vb = *(const float4*)&hbuf[arow_l * 68 + kc * 32 + quad * 8 + 4];
            const float xs[8] = {va.x, va.y, va.z, va.w, vb.x, vb.y, vb.z, vb.w};
            split16(xs, a3h[kc], a3l[kc]);
        }
        #pragma unroll
        for (int nt = 0; nt < 4; ++nt) {
            f32x4 acc = {0.0f, 0.0f, 0.0f, 0.0f};
            #pragma unroll
            for (int kc = 0; kc < 2; ++kc) {
                const long fo = (long)((kc * 4 + nt) * 64 + lane) * 8;
                const half8 wh = *(const half8*)(w3h + fo);
                const half8 wl = *(const half8*)(w3l + fo);
                acc = MFMA16(a3h[kc], wh, acc);
                acc = MFMA16(a3l[kc], wh, acc);
                acc = MFMA16(a3h[kc], wl, acc);
            }
            #pragma unroll
            for (int r = 0; r < 4; ++r)
                hbuf[(row0 + r) * 68 + nt * 16 + m] = acc[r] + bb3[nt];
        }
    }

    // A-frags (wave-local hbuf reads, before overwrite): fp16 screen operands
    half8 a0h, a1h;
    {
        const float* xrow = &hbuf[(w * 16 + m) * 68];
        const float4 xa = *(const float4*)(xrow + quad * 8);
        const float4 xb = *(const float4*)(xrow + quad * 8 + 4);
        const float4 xc = *(const float4*)(xrow + 32 + quad * 8);
        const float4 xd = *(const float4*)(xrow + 32 + quad * 8 + 4);
        const float x0[8] = {xa.x, xa.y, xa.z, xa.w, xb.x, xb.y, xb.z, xb.w};
        const float x1[8] = {xc.x, xc.y, xc.z, xc.w, xd.x, xd.y, xd.z, xd.w};
        #pragma unroll
        for (int j = 0; j < 8; ++j) {
            a0h[j] = (_Float16)x0[j];
            a1h[j] = (_Float16)x1[j];
        }
    }
    __syncthreads();    // all hbuf rows final (cross-wave reads next)

    // x -> msg (coalesced; rescore + loss read it back; then overwritten w/ q)
    {
        float4* mg = (float4*)(msg + base * OUT_DIM);
        #pragma unroll
        for (int mm = 0; mm < 4; ++mm) {
            const int v = t + NTHR * mm;
            const int p = v >> 4, k4 = v & 15;
            mg[v] = *(const float4*)&hbuf[p * 68 + k4 * 4];
        }
    }
    __syncthreads();    // hbuf reads done; staging may overwrite region0

    // ========== VQ scan: 4 x (stage 64 KB quarter -> 32 barrier-free tiles) =
    float bd[4] = {3.4e38f, 3.4e38f, 3.4e38f, 3.4e38f};
    int   bi[4] = {0, 0, 0, 0};

    for (int qp = 0; qp < 4; ++qp) {
        const _Float16* cbq = cbhp + (long)qp * 32768;  // 64 KB = 32768 halves
        #pragma unroll
        for (int j = 0; j < 8; ++j)
            gld16(smem + j * 8192 + w * 1024, cbq + j * 4096 + w * 512 + lane * 8);
        __syncthreads();    // implicit vmcnt drain: quarter resident

        #pragma unroll 4
        for (int tl = 0; tl < 32; ++tl) {
            const int g = qp * 32 + tl;
            const half8 th0 = *(const half8*)(smem + tl * 2048 + lane * 16);
            const half8 th1 = *(const half8*)(smem + tl * 2048 + 1024 + lane * 16);
            const float e2v = e2s[g * 16 + m];
            f32x4 acc = {0.0f, 0.0f, 0.0f, 0.0f};
            __builtin_amdgcn_s_setprio(1);
            acc = MFMA16(a0h, th0, acc);
            acc = MFMA16(a1h, th1, acc);
            __builtin_amdgcn_s_setprio(0);

            const int code = g * 16 + m;
            bool pushm[4]; int pip[4];
            #pragma unroll
            for (int r = 0; r < 4; ++r) {
                const float d = fmaf(-2.0f, acc[r], e2v);
                const bool lt = d < bd[r];
                // push loser iff within MARG of winner (== R3's two cases)
                pushm[r] = __builtin_fabsf(d - bd[r]) < MARG;
                pip[r] = lt ? bi[r] : code;
                bd[r] = lt ? d : bd[r];
                bi[r] = lt ? code : bi[r];
            }
            if (__any((int)(pushm[0] | pushm[1] | pushm[2] | pushm[3]))) {
                #pragma unroll
                for (int r = 0; r < 4; ++r) {
                    if (pushm[r]) {
                        const int slot = atomicAdd(&cand_cnt, 1);
                        if (slot < CAND_CAP)
                            cand_pc[slot] = ((w * 16 + quad * 4 + r) << 16) | pip[r];
                    }
                }
            }
        }
        __syncthreads();    // scan done before next stage overwrites region0
    }

    // per-point screened winner via 16-lane argmin butterfly; near-tie pushes
    {
        float rd[4]; int ri[4];
        #pragma unroll
        for (int r = 0; r < 4; ++r) { rd[r] = bd[r]; ri[r] = bi[r]; }
        #pragma unroll
        for (int off = 1; off <= 8; off <<= 1) {
            #pragma unroll
            for (int r = 0; r < 4; ++r) {
                const float od = __shfl_xor(rd[r], off, 64);
                const int   oi = __shfl_xor(ri[r], off, 64);
                if (od < rd[r] || (od == rd[r] && oi < ri[r])) {
                    rd[r] = od; ri[r] = oi;
                }
            }
        }
        #pragma unroll
        for (int r = 0; r < 4; ++r) {
            const int pl = w * 16 + quad * 4 + r;
            if (m == 0) win_sh[pl] = ri[r];
            if (bd[r] <= rd[r] + MARG && bi[r] != ri[r]) {
                const int slot = atomicAdd(&cand_cnt, 1);
                if (slot < CAND_CAP)
                    cand_pc[slot] = (pl << 16) | bi[r];
            }
        }
    }
    __syncthreads();    // win_sh + cand list final

    // exact fp32 rescore, parallel over all threads, packed atomicMin.
    // winners rescored unconditionally (immune to cand overflow, like R3).
    {
        if (t < BPTS) {
            const int n = win_sh[t];
            const float ex = exdist(msg + (base + t) * OUT_DIM,
                                    cb + (long)n * OUT_DIM, e2s[n]);
            atomicMin(&keys[t], packkey(ex, n));
        }
        const int L = min(cand_cnt, CAND_CAP);
        for (int l = t; l < L; l += NTHR) {
            const int pc = cand_pc[l];
            const int p = pc >> 16, n = pc & 0xFFFF;
            const float ex = exdist(msg + (base + p) * OUT_DIM,
                                    cb + (long)n * OUT_DIM, e2s[n]);
            atomicMin(&keys[p], packkey(ex, n));
        }
    }
    __syncthreads();

    if (t < BPTS) {
        const int code = (int)(keys[t] & 0xFFFFFFFFu);
        idx_sh[t] = code;
        idx_out[base + t] = (float)code;
    }
    __syncthreads();

    // gather q, write msg, accumulate loss (read-x / write-q same thread+addr)
    float lsum = 0.0f;
    float4* mg = (float4*)(msg + base * OUT_DIM);
    #pragma unroll
    for (int mm = 0; mm < 4; ++mm) {
        const int v = t + NTHR * mm;
        const int p = v >> 4, k4 = v & 15;
        const int code = idx_sh[p];
        const float4 q = ((const float4*)(cb + (long)code * OUT_DIM))[k4];
        const float4 xv = mg[v];
        const float dx = q.x - xv.x, dy = q.y - xv.y;
        const float dz = q.z - xv.z, dw2 = q.w - xv.w;
        lsum += dx * dx + dy * dy + dz * dz + dw2 * dw2;
        mg[v] = q;
    }
    #pragma unroll
    for (int off = 32; off > 0; off >>= 1) lsum += __shfl_down(lsum, off, 64);
    if (lane == 0) wred[w] = lsum;
    __syncthreads();
    if (t == 0) {
        float s = 0.0f;
        #pragma unroll
        for (int i = 0; i < NTHR / 64; ++i) s += wred[i];
        atomicAdd(loss_out, s * LOSS_SCALE);
    }
}

extern "C" void kernel_launch(void* const* d_in, const int* in_sizes, int n_in,
                              void* d_out, int out_size, void* d_ws, size_t ws_size,
                              hipStream_t stream) {
    const float* obs = (const float*)d_in[0];
    const float* W1  = (const float*)d_in[1];
    const float* b1  = (const float*)d_in[2];
    const float* W2  = (const float*)d_in[3];
    const float* b2  = (const float*)d_in[4];
    const float* W3  = (const float*)d_in[5];
    const float* b3  = (const float*)d_in[6];
    const float* cb  = (const float*)d_in[7];

    float* out  = (float*)d_out;
    float* msg  = out;
    float* idxf = out + MSG_ELEMS;
    float* loss = out + MSG_ELEMS + NPTS;

    char* ws = (char*)d_ws;
    float*     e2  = (float*)ws;                          // 8 KB
    _Float16*  cbh = (_Float16*)(ws + 8192);              // 256 KB (fp16)
    _Float16* w1h = (_Float16*)(ws + 532480);             // 16 KB
    _Float16* w1l = (_Float16*)(ws + 548864);             // 16 KB
    _Float16* w2h = (_Float16*)(ws + 565248);             // 8 KB
    _Float16* w2l = (_Float16*)(ws + 573440);             // 8 KB
    _Float16* w3h = (_Float16*)(ws + 581632);             // 8 KB
    _Float16* w3l = (_Float16*)(ws + 589824);             // 8 KB

    prep_all<<<80, 256, 0, stream>>>(cb, W1, W2, W3, e2, cbh,
                                     w1h, w1l, w2h, w2l, w3h, w3l, loss);
    fused_mlp_vq<<<NPTS / BPTS, NTHR, 0, stream>>>(
        obs, b1, b2, b3, w1h, w1l, w2h, w2l, w3h, w3l,
        cb, cbh, e2, msg, idxf, loss);
}

// Round 9
// 159.595 us; speedup vs baseline: 1.3166x; 1.0383x over previous
//
#include <hip/hip_runtime.h>

// VQSpeaker: obs[32,2048,128] -> 3-layer MLP -> x[65536,64] -> VQ argmin over
// codebook[2048,64] -> (msg = codebook[idx], idx, cmt_loss).
//
// Round 17: keep x LDS-resident for its entire life; double-buffered 16 KB
//   stage chunks (8 tiles/phase, staged UNDER the scan of the previous chunk).
//   R16 counters: WRITE 30 MB / FETCH 27 MB exposed the x->msg->readback
//   round-trip as the main remaining serialization. Now: hbuf[128][68] holds
//   x through A-frag build, exact rescore, and loss (all LDS reads); msg is
//   written once (q only). e2s LDS copy dropped (R13: global e2 reads fine).
//   LDS 73.8 KB -> still 2 blocks/CU. Stage latency hidden by scan (R14's
//   failure was 2-tile phases; 8-tile phases amortize, 1 barrier/phase).
//   Screen/candidates/rescore/loss semantics: R16-verbatim (bit-identical).
//
// d_out layout (float32): msg[4194304] | idx[65536] (as float) | loss[1]
// d_ws: e2[2048] | cbh fp16 256KB | w1h/w1l 16KB ea | w2h/w2l/w3h/w3l 8KB ea

#define NPTS    65536
#define IN_DIM  128
#define HID     64
#define OUT_DIM 64
#define CB_N    2048
#define MSG_ELEMS (NPTS * OUT_DIM)
#define LOSS_SCALE (1.0f / 4194304.0f)
#define MARG 0.5f          // R3-proven screening margin
#define CAND_CAP 1024      // 8 per point
#define BPTS 128           // points per block (8 waves x 16)
#define NTHR 512

typedef __attribute__((ext_vector_type(8))) short short8;
typedef _Float16 half8 __attribute__((ext_vector_type(8)));
typedef __attribute__((ext_vector_type(4))) float f32x4;
typedef unsigned int u32;
typedef unsigned long long u64;

// async global->LDS, 16B/lane: LDS dest = wave-uniform base + lane*16
__device__ __forceinline__ void gld16(void* lds_base, const void* gsrc) {
    __builtin_amdgcn_global_load_lds(
        (const __attribute__((address_space(1))) u32*)gsrc,
        (__attribute__((address_space(3))) u32*)lds_base, 16, 0, 0);
}

// ---- merged prep, 80 blocks: 0-63 prep_cb, 64-71 prep_w, 72-79 e2(+loss) --
__global__ __launch_bounds__(256) void prep_all(
    const float* __restrict__ cb,
    const float* __restrict__ W1, const float* __restrict__ W2,
    const float* __restrict__ W3,
    float* __restrict__ e2,
    _Float16* __restrict__ cbh,
    _Float16* __restrict__ w1h, _Float16* __restrict__ w1l,
    _Float16* __restrict__ w2h, _Float16* __restrict__ w2l,
    _Float16* __restrict__ w3h, _Float16* __restrict__ w3l,
    float* __restrict__ loss)
{
    const int b = blockIdx.x, tid = threadIdx.x;
    if (b < 64) {
        // ---- prep_cb: one (code n, half h, quad) per thread ----
        const int id = b * 256 + tid;               // 0..16383
        const int n = id >> 3, h = (id >> 2) & 1, quad = id & 3;
        const int t = n >> 4, l15 = n & 15;
        const float* src = cb + (long)n * OUT_DIM + h * 32 + quad * 8;
        half8 hi;
        #pragma unroll
        for (int j = 0; j < 8; ++j)
            hi[j] = (_Float16)src[j];
        const long dst = ((long)(t * 2 + h) * 64 + quad * 16 + l15) * 8;
        *(half8*)(cbh + dst) = hi;
    } else if (b < 72) {
        // ---- prep_w: W1/W2/W3 -> MFMA B-frag order, fp16 hi/lo split ----
        const int id = (b - 64) * 256 + tid;        // 0..2047
        const int lane = id & 63;
        const int m = lane & 15, quad = lane >> 4;
        const float* W; _Float16 *dh, *dl; int frag;
        if (id < 1024)      { W = W1; dh = w1h; dl = w1l; frag = id >> 6; }
        else if (id < 1536) { W = W2; dh = w2h; dl = w2l; frag = (id - 1024) >> 6; }
        else                { W = W3; dh = w3h; dl = w3l; frag = (id - 1536) >> 6; }
        const int kc = frag >> 2, nt = frag & 3;
        half8 hi, lo;
        #pragma unroll
        for (int j = 0; j < 8; ++j) {
            const float v = W[(long)(kc * 32 + quad * 8 + j) * 64 + nt * 16 + m];
            hi[j] = (_Float16)v;
            lo[j] = (_Float16)(v - (float)hi[j]);
        }
        const long dst = (long)(frag * 64 + lane) * 8;
        *(half8*)(dh + dst) = hi;
        *(half8*)(dl + dst) = lo;
    } else {
        // ---- e2 + zero_loss ----
        if (b == 72 && tid == 0) *loss = 0.0f;
        const int c = (b - 72) * 256 + tid;
        const float4* row = (const float4*)(cb + (long)c * OUT_DIM);
        float s = 0.0f;
        #pragma unroll
        for (int mq = 0; mq < 16; ++mq) {
            const float4 v = row[mq];
            s += v.x * v.x + v.y * v.y + v.z * v.z + v.w * v.w;
        }
        e2[c] = s;
    }
}

#define MFMA16(A, B, C) __builtin_amdgcn_mfma_f32_16x16x32_f16(A, B, C, 0, 0, 0)

__device__ __forceinline__ void split16(const float* xs, half8& h, half8& l) {
    #pragma unroll
    for (int j = 0; j < 8; ++j) {
        h[j] = (_Float16)xs[j];
        l[j] = (_Float16)(xs[j] - (float)h[j]);
    }
}

// packed rescore key: (total-order fp32 dist << 32) | code.
// min over keys == (min dist, tie -> min code) == reference argmin semantics.
__device__ __forceinline__ u64 packkey(float d, int n) {
    u32 ub = __float_as_uint(d);
    ub = (ub & 0x80000000u) ? ~ub : (ub | 0x80000000u);
    return ((u64)ub << 32) | (u32)n;
}

// exact fp32 distance (R2/R3-proven pairing); xr is LDS, cbrow global.
__device__ __forceinline__ float exdist(
    const float* xr, const float* __restrict__ cbrow, float e2v)
{
    const float4* xp = (const float4*)xr;
    const float4* cp = (const float4*)cbrow;
    float a0 = 0.0f, a1 = 0.0f;
    #pragma unroll
    for (int mq = 0; mq < 16; ++mq) {
        const float4 xv = xp[mq], cv = cp[mq];
        a0 = fmaf(xv.x, cv.x, a0); a1 = fmaf(xv.y, cv.y, a1);
        a0 = fmaf(xv.z, cv.z, a0); a1 = fmaf(xv.w, cv.w, a1);
    }
    return fmaf(-2.0f, a0 + a1, e2v);
}

// ---------------- FUSED: MLP + VQ, x LDS-resident end-to-end ---------------
__global__ __launch_bounds__(NTHR, 4) void fused_mlp_vq(
    const float* __restrict__ obs,
    const float* __restrict__ b1, const float* __restrict__ b2,
    const float* __restrict__ b3,
    const _Float16* __restrict__ w1h, const _Float16* __restrict__ w1l,
    const _Float16* __restrict__ w2h, const _Float16* __restrict__ w2l,
    const _Float16* __restrict__ w3h, const _Float16* __restrict__ w3l,
    const float* __restrict__ cb,
    const _Float16* __restrict__ cbhp,
    const float* __restrict__ e2,
    float* __restrict__ msg,        // out only: quantize
    float* __restrict__ idx_out,
    float* __restrict__ loss_out)
{
    __shared__ float hbuf[BPTS * 68];       // 34.8 KB: mlp scratch then x
    __shared__ __align__(16) char stg[2][16384];  // 32 KB stage double buffer
    __shared__ int   cand_pc[CAND_CAP];     // 4 KB: (p_local<<16) | code
    __shared__ u64   keys[BPTS];            // packed rescore keys
    __shared__ int   win_sh[BPTS];          // screened winners
    __shared__ int   idx_sh[BPTS];
    __shared__ float wred[NTHR / 64];
    __shared__ int   cand_cnt;

    const int t = threadIdx.x, lane = t & 63, w = t >> 6;
    const int m = lane & 15, quad = lane >> 4;
    const long base = (long)blockIdx.x * BPTS;
    const int row0 = w * 16 + quad * 4;         // C-layout write rows (+r)
    const int arow_l = w * 16 + m;              // A-layout read row

    if (t == 0) cand_cnt = 0;
    if (t < BPTS) keys[t] = ~0ULL;

    // ================= MLP phase (R13-verbatim, wave-local, 8 waves) ========
    {
        float bb1[4], bb2[4], bb3[4];
        #pragma unroll
        for (int nt = 0; nt < 4; ++nt) {
            bb1[nt] = b1[nt * 16 + m];
            bb2[nt] = b2[nt * 16 + m];
            bb3[nt] = b3[nt * 16 + m];
        }

        const float* arow = obs + (base + w * 16 + m) * IN_DIM;
        half8 a1h[4], a1l[4];
        #pragma unroll
        for (int kc = 0; kc < 4; ++kc) {
            const float4 va = *(const float4*)(arow + kc * 32 + quad * 8);
            const float4 vb = *(const float4*)(arow + kc * 32 + quad * 8 + 4);
            const float xs[8] = {va.x, va.y, va.z, va.w, vb.x, vb.y, vb.z, vb.w};
            split16(xs, a1h[kc], a1l[kc]);
        }

        // layer 1
        #pragma unroll
        for (int nt = 0; nt < 4; ++nt) {
            f32x4 acc = {0.0f, 0.0f, 0.0f, 0.0f};
            #pragma unroll
            for (int kc = 0; kc < 4; ++kc) {
                const long fo = (long)((kc * 4 + nt) * 64 + lane) * 8;
                const half8 wh = *(const half8*)(w1h + fo);
                const half8 wl = *(const half8*)(w1l + fo);
                acc = MFMA16(a1h[kc], wh, acc);
                acc = MFMA16(a1l[kc], wh, acc);
                acc = MFMA16(a1h[kc], wl, acc);
            }
            #pragma unroll
            for (int r = 0; r < 4; ++r) {
                const float v = acc[r] + bb1[nt];
                hbuf[(row0 + r) * 68 + nt * 16 + m] = v > 0.0f ? v : 0.0f;
            }
        }

        // layer 2
        half8 a2h[2], a2l[2];
        #pragma unroll
        for (int kc = 0; kc < 2; ++kc) {
            const float4 va = *(const float4*)&hbuf[arow_l * 68 + kc * 32 + quad * 8];
            const float4 vb = *(const float4*)&hbuf[arow_l * 68 + kc * 32 + quad * 8 + 4];
            const float xs[8] = {va.x, va.y, va.z, va.w, vb.x, vb.y, vb.z, vb.w};
            split16(xs, a2h[kc], a2l[kc]);
        }
        #pragma unroll
        for (int nt = 0; nt < 4; ++nt) {
            f32x4 acc = {0.0f, 0.0f, 0.0f, 0.0f};
            #pragma unroll
            for (int kc = 0; kc < 2; ++kc) {
                const long fo = (long)((kc * 4 + nt) * 64 + lane) * 8;
                const half8 wh = *(const half8*)(w2h + fo);
                const half8 wl = *(const half8*)(w2l + fo);
                acc = MFMA16(a2h[kc], wh, acc);
                acc = MFMA16(a2l[kc], wh, acc);
                acc = MFMA16(a2h[kc], wl, acc);
            }
            #pragma unroll
            for (int r = 0; r < 4; ++r) {
                const float v = acc[r] + bb2[nt];
                hbuf[(row0 + r) * 68 + nt * 16 + m] = v > 0.0f ? v : 0.0f;
            }
        }

        // layer 3 -> x rows in hbuf (stay resident until kernel end)
        half8 a3h[2], a3l[2];
        #pragma unroll
        for (int kc = 0; kc < 2; ++kc) {
            const float4 va = *(const float4*)&hbuf[arow_l * 68 + kc * 32 + quad * 8];
            const float4 vb = *(const float4*)&hbuf[arow_l * 68 + kc * 32 + quad * 8 + 4];
            const float xs[8] = {va.x, va.y, va.z, va.w, vb.x, vb.y, vb.z, vb.w};
            split16(xs, a3h[kc], a3l[kc]);
        }
        #pragma unroll
        for (int nt = 0; nt < 4; ++nt) {
            f32x4 acc = {0.0f, 0.0f, 0.0f, 0.0f};
            #pragma unroll
            for (int kc = 0; kc < 2; ++kc) {
                const long fo = (long)((kc * 4 + nt) * 64 + lane) * 8;
                const half8 wh = *(const half8*)(w3h + fo);
                const half8 wl = *(const half8*)(w3l + fo);
                acc = MFMA16(a3h[kc], wh, acc);
                acc = MFMA16(a3l[kc], wh, acc);
                acc = MFMA16(a3h[kc], wl, acc);
            }
            #pragma unroll
            for (int r = 0; r < 4; ++r)
                hbuf[(row0 + r) * 68 + nt * 16 + m] = acc[r] + bb3[nt];
        }
    }

    // A-frags (wave-local hbuf rows): fp16 screen operands
    half8 a0h, a1h;
    {
        const float* xrow = &hbuf[(w * 16 + m) * 68];
        const float4 xa = *(const float4*)(xrow + quad * 8);
        const float4 xb = *(const float4*)(xrow + quad * 8 + 4);
        const float4 xc = *(const float4*)(xrow + 32 + quad * 8);
        const float4 xd = *(const float4*)(xrow + 32 + quad * 8 + 4);
        const float x0[8] = {xa.x, xa.y, xa.z, xa.w, xb.x, xb.y, xb.z, xb.w};
        const float x1[8] = {xc.x, xc.y, xc.z, xc.w, xd.x, xd.y, xd.z, xd.w};
        #pragma unroll
        for (int j = 0; j < 8; ++j) {
            a0h[j] = (_Float16)x0[j];
            a1h[j] = (_Float16)x1[j];
        }
    }

    // prologue: stage phase 0 (tiles 0-7, 16 KB) into buf0; 2 gld16 per wave
    #pragma unroll
    for (int j = 0; j < 2; ++j)
        gld16(stg[0] + (w * 2 + j) * 1024,
              cbhp + (w * 2 + j) * 512 + lane * 8);
    __syncthreads();   // drains stage-0; hbuf + cand_cnt + keys visible

    // ========== VQ scan: 16 phases x 8 tiles, stage hidden under scan =======
    float bd[4] = {3.4e38f, 3.4e38f, 3.4e38f, 3.4e38f};
    int   bi[4] = {0, 0, 0, 0};

    for (int ph = 0; ph < 16; ++ph) {
        if (ph < 15) {      // stage next chunk into the other buffer
            const _Float16* cbq = cbhp + (long)(ph + 1) * 8192;
            #pragma unroll
            for (int j = 0; j < 2; ++j)
                gld16(stg[(ph + 1) & 1] + (w * 2 + j) * 1024,
                      cbq + (w * 2 + j) * 512 + lane * 8);
        }
        const char* bufp = stg[ph & 1];
        #pragma unroll
        for (int tl = 0; tl < 8; ++tl) {
            const int g = ph * 8 + tl;
            const half8 th0 = *(const half8*)(bufp + tl * 2048 + lane * 16);
            const half8 th1 = *(const half8*)(bufp + tl * 2048 + 1024 + lane * 16);
            const float e2v = e2[g * 16 + m];
            f32x4 acc = {0.0f, 0.0f, 0.0f, 0.0f};
            __builtin_amdgcn_s_setprio(1);
            acc = MFMA16(a0h, th0, acc);
            acc = MFMA16(a1h, th1, acc);
            __builtin_amdgcn_s_setprio(0);

            const int code = g * 16 + m;
            bool pushm[4]; int pip[4];
            #pragma unroll
            for (int r = 0; r < 4; ++r) {
                const float d = fmaf(-2.0f, acc[r], e2v);
                const bool lt = d < bd[r];
                // push loser iff within MARG of winner (== R3's two cases)
                pushm[r] = __builtin_fabsf(d - bd[r]) < MARG;
                pip[r] = lt ? bi[r] : code;
                bd[r] = lt ? d : bd[r];
                bi[r] = lt ? code : bi[r];
            }
            if (__any((int)(pushm[0] | pushm[1] | pushm[2] | pushm[3]))) {
                #pragma unroll
                for (int r = 0; r < 4; ++r) {
                    if (pushm[r]) {
                        const int slot = atomicAdd(&cand_cnt, 1);
                        if (slot < CAND_CAP)
                            cand_pc[slot] = ((w * 16 + quad * 4 + r) << 16) | pip[r];
                    }
                }
            }
        }
        __syncthreads();    // scan of buf done; next-phase stage drained
    }

    // per-point screened winner via 16-lane argmin butterfly; near-tie pushes
    {
        float rd[4]; int ri[4];
        #pragma unroll
        for (int r = 0; r < 4; ++r) { rd[r] = bd[r]; ri[r] = bi[r]; }
        #pragma unroll
        for (int off = 1; off <= 8; off <<= 1) {
            #pragma unroll
            for (int r = 0; r < 4; ++r) {
                const float od = __shfl_xor(rd[r], off, 64);
                const int   oi = __shfl_xor(ri[r], off, 64);
                if (od < rd[r] || (od == rd[r] && oi < ri[r])) {
                    rd[r] = od; ri[r] = oi;
                }
            }
        }
        #pragma unroll
        for (int r = 0; r < 4; ++r) {
            const int pl = w * 16 + quad * 4 + r;
            if (m == 0) win_sh[pl] = ri[r];
            if (bd[r] <= rd[r] + MARG && bi[r] != ri[r]) {
                const int slot = atomicAdd(&cand_cnt, 1);
                if (slot < CAND_CAP)
                    cand_pc[slot] = (pl << 16) | bi[r];
            }
        }
    }
    __syncthreads();    // win_sh + cand list final

    // exact fp32 rescore (x from LDS, cb rows from global/L2), atomicMin keys
    {
        if (t < BPTS) {
            const int n = win_sh[t];
            const float ex = exdist(&hbuf[t * 68], cb + (long)n * OUT_DIM, e2[n]);
            atomicMin(&keys[t], packkey(ex, n));
        }
        const int L = min(cand_cnt, CAND_CAP);
        for (int l = t; l < L; l += NTHR) {
            const int pc = cand_pc[l];
            const int p = pc >> 16, n = pc & 0xFFFF;
            const float ex = exdist(&hbuf[p * 68], cb + (long)n * OUT_DIM, e2[n]);
            atomicMin(&keys[p], packkey(ex, n));
        }
    }
    __syncthreads();

    if (t < BPTS) {
        const int code = (int)(keys[t] & 0xFFFFFFFFu);
        idx_sh[t] = code;
        idx_out[base + t] = (float)code;
    }
    __syncthreads();

    // gather q, write msg (only write), accumulate loss (x from LDS)
    float lsum = 0.0f;
    float4* mg = (float4*)(msg + base * OUT_DIM);
    #pragma unroll
    for (int mm = 0; mm < 4; ++mm) {
        const int v = t + NTHR * mm;
        const int p = v >> 4, k4 = v & 15;
        const int code = idx_sh[p];
        const float4 q = ((const float4*)(cb + (long)code * OUT_DIM))[k4];
        const float4 xv = *(const float4*)&hbuf[p * 68 + k4 * 4];
        const float dx = q.x - xv.x, dy = q.y - xv.y;
        const float dz = q.z - xv.z, dw2 = q.w - xv.w;
        lsum += dx * dx + dy * dy + dz * dz + dw2 * dw2;
        mg[v] = q;
    }
    #pragma unroll
    for (int off = 32; off > 0; off >>= 1) lsum += __shfl_down(lsum, off, 64);
    if (lane == 0) wred[w] = lsum;
    __syncthreads();
    if (t == 0) {
        float s = 0.0f;
        #pragma unroll
        for (int i = 0; i < NTHR / 64; ++i) s += wred[i];
        atomicAdd(loss_out, s * LOSS_SCALE);
    }
}

extern "C" void kernel_launch(void* const* d_in, const int* in_sizes, int n_in,
                              void* d_out, int out_size, void* d_ws, size_t ws_size,
                              hipStream_t stream) {
    const float* obs = (const float*)d_in[0];
    const float* W1  = (const float*)d_in[1];
    const float* b1  = (const float*)d_in[2];
    const float* W2  = (const float*)d_in[3];
    const float* b2  = (const float*)d_in[4];
    const float* W3  = (const float*)d_in[5];
    const float* b3  = (const float*)d_in[6];
    const float* cb  = (const float*)d_in[7];

    float* out  = (float*)d_out;
    float* msg  = out;
    float* idxf = out + MSG_ELEMS;
    float* loss = out + MSG_ELEMS + NPTS;

    char* ws = (char*)d_ws;
    float*     e2  = (float*)ws;                          // 8 KB
    _Float16*  cbh = (_Float16*)(ws + 8192);              // 256 KB (fp16)
    _Float16* w1h = (_Float16*)(ws + 532480);             // 16 KB
    _Float16* w1l = (_Float16*)(ws + 548864);             // 16 KB
    _Float16* w2h = (_Float16*)(ws + 565248);             // 8 KB
    _Float16* w2l = (_Float16*)(ws + 573440);             // 8 KB
    _Float16* w3h = (_Float16*)(ws + 581632);             // 8 KB
    _Float16* w3l = (_Float16*)(ws + 589824);             // 8 KB

    prep_all<<<80, 256, 0, stream>>>(cb, W1, W2, W3, e2, cbh,
                                     w1h, w1l, w2h, w2l, w3h, w3l, loss);
    fused_mlp_vq<<<NPTS / BPTS, NTHR, 0, stream>>>(
        obs, b1, b2, b3, w1h, w1l, w2h, w2l, w3h, w3l,
        cb, cbh, e2, msg, idxf, loss);
}